// Round 1
// baseline (87.787 us; speedup 1.0000x reference)
//
#include <hip/hip_runtime.h>

typedef __attribute__((ext_vector_type(8))) short short8;
typedef __attribute__((ext_vector_type(4))) float f32x4;
typedef unsigned short u16;

#define NROW 32768   // circuits = 4096*8
#define KDIM 256
#define NOUT 512

// ---------------- gate tables (kind: 0=ry 1=rx 2=xx 3=xy 4=cry 5=crx) --------
__device__ __constant__ unsigned char GK[114] = {
  0,0,0,0,0,0,0,0,0,             // ry 0-8
  1,1,1,1,1,1,1,1,1,             // rx 9-17
  2,2,2,2,2,2,2,2,               // xx 18-25
  4,4,4,4,4,4,4,4,               // cry 26-33
  0,0,0,0,0,0,0,0,0,             // ry 34-42
  3,3,3,3,3,3,3,3,               // xy 43-50
  5,5,5,5,5,5,                   // crx 51-56
  1,1,1,1,1,1,1,1,1,             // rx 57-65
  2,2,2,2,2,2,2,2,               // xx 66-73
  4,4,4,4,4,4,4,4,               // cry 74-81
  0,0,0,0,0,0,0,0,0,             // ry 82-90
  3,3,3,3,3,3,3,3,               // xy 91-98
  5,5,5,5,5,5,                   // crx 99-104
  1,1,1,1,1,1,1,1,1              // rx 105-113
};
__device__ __constant__ unsigned char GW0[114] = {
  0,1,2,3,4,5,6,7,8,
  0,1,2,3,4,5,6,7,8,
  0,8,1,7,2,6,3,5,
  0,1,2,8,7,6,5,3,
  0,1,2,3,4,5,6,7,8,
  4,4,3,5,2,6,1,7,
  0,2,5,7,1,6,
  0,1,2,3,4,5,6,7,8,
  0,8,1,7,2,6,3,5,
  0,1,2,8,7,6,5,3,
  0,1,2,3,4,5,6,7,8,
  4,4,3,5,2,6,1,7,
  0,2,5,7,1,6,
  0,1,2,3,4,5,6,7,8
};
__device__ __constant__ unsigned char GW1[114] = {
  0,0,0,0,0,0,0,0,0,
  0,0,0,0,0,0,0,0,0,
  1,7,2,6,3,5,4,4,
  1,2,3,7,6,5,4,4,
  0,0,0,0,0,0,0,0,0,
  3,5,2,6,1,7,0,8,
  1,3,6,8,2,7,
  0,0,0,0,0,0,0,0,0,
  1,7,2,6,3,5,4,4,
  1,2,3,7,6,5,4,4,
  0,0,0,0,0,0,0,0,0,
  3,5,2,6,1,7,0,8,
  1,3,6,8,2,7,
  0,0,0,0,0,0,0,0,0
};

__device__ __forceinline__ u16 f2bf(float f) {
  unsigned int u = __float_as_uint(f);
  u = (u + 0x7fffu + ((u >> 16) & 1u)) >> 16;
  return (u16)u;
}
__device__ __forceinline__ float bf2f(u16 b) {
  return __uint_as_float(((unsigned int)b) << 16);
}

typedef const __attribute__((address_space(1))) unsigned int* gptr_t;
typedef __attribute__((address_space(3))) unsigned int* lptr_t;
__device__ __forceinline__ void gload16(const void* g, void* l) {
  __builtin_amdgcn_global_load_lds((gptr_t)g, (lptr_t)l, 16, 0, 0);
}

// ---------------- kernel 1: g = tanh(x)*pi/2 -> bf16, invn2 = 1/sum(g^2) ----
__global__ void prep_g(const float* __restrict__ x, u16* __restrict__ G,
                       float* __restrict__ invn2) {
  int gid = blockIdx.x * 256 + threadIdx.x;
  int row = gid >> 6;
  int l = gid & 63;
  const float H = 1.5707963267948966f;
  float4 v = *(const float4*)(x + ((size_t)row << 8) + l * 4);
  float g0 = tanhf(v.x) * H, g1 = tanhf(v.y) * H;
  float g2 = tanhf(v.z) * H, g3 = tanhf(v.w) * H;
  u16 b0 = f2bf(g0), b1 = f2bf(g1), b2 = f2bf(g2), b3 = f2bf(g3);
  float r0 = bf2f(b0), r1 = bf2f(b1), r2 = bf2f(b2), r3 = bf2f(b3);
  float sum = r0 * r0 + r1 * r1 + r2 * r2 + r3 * r3;
  #pragma unroll
  for (int o = 32; o; o >>= 1) sum += __shfl_xor(sum, o, 64);
  ushort4 pk; pk.x = b0; pk.y = b1; pk.z = b2; pk.w = b3;
  *(ushort4*)(G + ((size_t)row << 8) + l * 4) = pk;
  if (l == 0) invn2[row] = 1.0f / sum;
}

// ---------------- kernel 2: build M columns (256 blocks, one basis state) ---
// state index: wire 0 = MSB: idx = sum_w bit_w << (8-w)
// embedding col k -> basis index ((k>>4)<<5) | (k&15)   (wire 4 = 0)
__global__ void build_m(const float* __restrict__ qp, u16* __restrict__ BreT,
                        u16* __restrict__ BimT) {
  __shared__ float2 st[512];
  __shared__ float lc[114], ls[114];
  int t = threadIdx.x;
  int k = blockIdx.x;
  st[t] = make_float2(0.f, 0.f);
  st[t + 256] = make_float2(0.f, 0.f);
  if (t < 114) {
    float a = qp[t] * 0.5f;
    lc[t] = cosf(a);
    ls[t] = sinf(a);
  }
  __syncthreads();
  if (t == 0) {
    int col = ((k >> 4) << 5) | (k & 15);
    st[col] = make_float2(1.f, 0.f);
  }
  for (int g = 0; g < 114; ++g) {
    __syncthreads();
    int kind = GK[g];
    float c = lc[g], s = ls[g];
    int p0 = 8 - GW0[g];
    if (kind <= 1) {
      int i0 = ((t >> p0) << (p0 + 1)) | (t & ((1 << p0) - 1));
      int i1 = i0 | (1 << p0);
      float2 a0 = st[i0], a1 = st[i1], n0, n1;
      if (kind == 0) {  // ry: [[c,-s],[s,c]]
        n0 = make_float2(c * a0.x - s * a1.x, c * a0.y - s * a1.y);
        n1 = make_float2(s * a0.x + c * a1.x, s * a0.y + c * a1.y);
      } else {          // rx: [[c,-is],[-is,c]]
        n0 = make_float2(c * a0.x + s * a1.y, c * a0.y - s * a1.x);
        n1 = make_float2(c * a1.x + s * a0.y, c * a1.y - s * a0.x);
      }
      st[i0] = n0; st[i1] = n1;
    } else {
      int p1 = 8 - GW1[g];
      int ph = p0 > p1 ? p0 : p1;
      int pl = p0 > p1 ? p1 : p0;
      int f = t & 127;
      int low = f & ((1 << pl) - 1);
      int b = f >> pl;
      int mid = b & ((1 << (ph - pl - 1)) - 1);
      int hi = b >> (ph - pl - 1);
      int base = (hi << (ph + 1)) | (mid << (pl + 1)) | low;
      int m0 = 1 << p0, m1 = 1 << p1;
      if (kind == 2) {  // xx: couples (00,11) and (01,10) with [c,-is;-is,c]
        int cls = t >> 7;
        int iA = base | (cls ? m1 : 0);
        int iB = base | m0 | (cls ? 0 : m1);
        float2 A = st[iA], B = st[iB];
        float2 nA = make_float2(c * A.x + s * B.y, c * A.y - s * B.x);
        float2 nB = make_float2(c * B.x + s * A.y, c * B.y - s * A.x);
        st[iA] = nA; st[iB] = nB;
      } else if (t < 128) {
        if (kind == 3) {  // xy: couples (01,10) with [c,is;is,c]
          int iA = base | m1, iB = base | m0;
          float2 A = st[iA], B = st[iB];
          float2 nA = make_float2(c * A.x - s * B.y, c * A.y + s * B.x);
          float2 nB = make_float2(c * B.x - s * A.y, c * B.y + s * A.x);
          st[iA] = nA; st[iB] = nB;
        } else {          // cry/crx on (ctrl=1) pairs (10)<->(11)
          int i0 = base | m0, i1 = base | m0 | m1;
          float2 a0 = st[i0], a1 = st[i1], n0, n1;
          if (kind == 4) {
            n0 = make_float2(c * a0.x - s * a1.x, c * a0.y - s * a1.y);
            n1 = make_float2(s * a0.x + c * a1.x, s * a0.y + c * a1.y);
          } else {
            n0 = make_float2(c * a0.x + s * a1.y, c * a0.y - s * a1.x);
            n1 = make_float2(c * a1.x + s * a0.y, c * a1.y - s * a0.x);
          }
          st[i0] = n0; st[i1] = n1;
        }
      }
    }
  }
  __syncthreads();
  // write transposed: BreT[j][k], row stride KDIM (for GEMM B^T fragment reads)
  for (int j = t; j < 512; j += 256) {
    BreT[(size_t)j * KDIM + k] = f2bf(st[j].x);
    BimT[(size_t)j * KDIM + k] = f2bf(st[j].y);
  }
}

// ---------------- kernel 3: GEMM + |.|^2 epilogue -----------------------------
// C[32768 x 512]: acc_re = G x Bre^T, acc_im = G x Bim^T, p = (re^2+im^2)*invn2
// BM=128 BN=64 BK=64, 256 threads (4 waves), wave w owns rows w*32..w*32+31
__global__ void __launch_bounds__(256) gemm_probs(
    const u16* __restrict__ G, const u16* __restrict__ BreT,
    const u16* __restrict__ BimT, const float* __restrict__ invn2,
    float* __restrict__ out) {
  __shared__ __align__(16) char lds[32768];
  char* sA = lds;            // 128 rows x 128B = 16KB
  char* sBre = lds + 16384;  // 64 x 128B = 8KB
  char* sBim = lds + 24576;  // 8KB
  int tid = threadIdx.x;
  int l = tid & 63;
  int w = tid >> 6;
  int n0 = blockIdx.x * 64;
  int row0 = blockIdx.y * 128;

  f32x4 accre[2][4] = {};
  f32x4 accim[2][4] = {};

  for (int k0 = 0; k0 < KDIM; k0 += 64) {
    __syncthreads();
    // stage A tile: 16 segs of 8 rows (1KB each); XOR-swizzle on SOURCE addr
    #pragma unroll
    for (int i = 0; i < 4; ++i) {
      int sg = w * 4 + i;
      int row = sg * 8 + (l >> 3);
      int chunk = (l & 7) ^ (row & 7);
      gload16(G + (size_t)(row0 + row) * KDIM + k0 + chunk * 8, sA + sg * 1024);
    }
    // stage B tiles: 8 segs each
    #pragma unroll
    for (int i = 0; i < 2; ++i) {
      int sg = w * 2 + i;
      int rn = sg * 8 + (l >> 3);
      int chunk = (l & 7) ^ (rn & 7);
      size_t off = (size_t)(n0 + rn) * KDIM + k0 + chunk * 8;
      gload16(BreT + off, sBre + sg * 1024);
      gload16(BimT + off, sBim + sg * 1024);
    }
    asm volatile("s_waitcnt vmcnt(0)" ::: "memory");
    __syncthreads();

    short8 aF[2][2], brF[4][2], biF[4][2];
    #pragma unroll
    for (int kk = 0; kk < 2; ++kk) {
      #pragma unroll
      for (int mr = 0; mr < 2; ++mr) {
        int row = w * 32 + mr * 16 + (l & 15);
        int chunk = (kk * 4 + (l >> 4)) ^ (row & 7);
        aF[mr][kk] = *(const short8*)(sA + row * 128 + chunk * 16);
      }
      #pragma unroll
      for (int nb = 0; nb < 4; ++nb) {
        int rn = nb * 16 + (l & 15);
        int chunk = (kk * 4 + (l >> 4)) ^ (rn & 7);
        brF[nb][kk] = *(const short8*)(sBre + rn * 128 + chunk * 16);
        biF[nb][kk] = *(const short8*)(sBim + rn * 128 + chunk * 16);
      }
    }
    #pragma unroll
    for (int kk = 0; kk < 2; ++kk)
      #pragma unroll
      for (int mr = 0; mr < 2; ++mr)
        #pragma unroll
        for (int nb = 0; nb < 4; ++nb) {
          accre[mr][nb] = __builtin_amdgcn_mfma_f32_16x16x32_bf16(
              aF[mr][kk], brF[nb][kk], accre[mr][nb], 0, 0, 0);
          accim[mr][nb] = __builtin_amdgcn_mfma_f32_16x16x32_bf16(
              aF[mr][kk], biF[nb][kk], accim[mr][nb], 0, 0, 0);
        }
  }

  // epilogue: C/D layout col=lane&15, row=(lane>>4)*4+reg
  #pragma unroll
  for (int mr = 0; mr < 2; ++mr) {
    int rbase = row0 + w * 32 + mr * 16 + (l >> 4) * 4;
    #pragma unroll
    for (int reg = 0; reg < 4; ++reg) {
      float inv = invn2[rbase + reg];
      #pragma unroll
      for (int nb = 0; nb < 4; ++nb) {
        float re = accre[mr][nb][reg];
        float im = accim[mr][nb][reg];
        out[(size_t)(rbase + reg) * NOUT + n0 + nb * 16 + (l & 15)] =
            (re * re + im * im) * inv;
      }
    }
  }
}

extern "C" void kernel_launch(void* const* d_in, const int* in_sizes, int n_in,
                              void* d_out, int out_size, void* d_ws,
                              size_t ws_size, hipStream_t stream) {
  const float* x = (const float*)d_in[0];   // (4096, 2048) f32
  const float* qp = (const float*)d_in[1];  // (114,) f32
  float* out = (float*)d_out;               // 32768*512 f32
  char* ws = (char*)d_ws;
  u16* G = (u16*)ws;                                   // 16 MB
  u16* BreT = (u16*)(ws + (16u << 20));                // 256 KB
  u16* BimT = (u16*)(ws + (16u << 20) + (256u << 10)); // 256 KB
  float* invn2 = (float*)(ws + (16u << 20) + (512u << 10));  // 128 KB

  hipLaunchKernelGGL(prep_g, dim3(NROW / 4), dim3(256), 0, stream, x, G, invn2);
  hipLaunchKernelGGL(build_m, dim3(256), dim3(256), 0, stream, qp, BreT, BimT);
  hipLaunchKernelGGL(gemm_probs, dim3(NOUT / 64, NROW / 128), dim3(256), 0,
                     stream, G, BreT, BimT, invn2, out);
}